// Round 4
// baseline (189.960 us; speedup 1.0000x reference)
//
#include <hip/hip_runtime.h>

// ---------------------------------------------------------------------------
// DeepLagrangianNetwork head, MFMA version — round 8.
// Round-7 post-mortem: latency-bound at ~20% per-SIMD issue. VGPR=68 means
// the declared persistent set (afrag 32 + head weights 48 + b2v 16) did NOT
// fit -> compiler rematerialized head-weight loads inside the it-loop
// (12 L1 loads + vmcnt waits per it). Fixes this round:
//   1. __launch_bounds__(128,4): grant the full 128-VGPR budget (occupancy
//      cap at 4 waves/SIMD is unchanged vs 68 regs) so all weights stay
//      register-resident -> no remat VMEM stalls in the inner loop.
//   2. Heads phase in packed f32 (v_pk_fma_f32 / v_pk_max_f32 via f32x2):
//      acc quads + wld f32x4s are adjacent reg pairs, pairing is mov-free.
//      -160 VALU instrs per 64-row group, bit-exact fp32.
// Structure otherwise = round 7: 128-thr blocks (2 waves), 2 row-groups,
// 16 KiB LDS, zero __syncthreads (wave-self-contained).
// Per row: h1 = lrelu(q@W1^T+b1)  (4->64, VALU, v_cvt_pk_bf16 packing)
//          h2^T = W2 @ h1^T       (bf16 MFMA 16x16x32, A = W2 tiles)
//          heads (Ld, Lo) on fp32 h2 in-register, quad-reduced via shfl_xor
//          H = L L^T + 1e-9 I (2x2), one coalesced float4 store per row.
// Fragment layouts (m89/m120-verified):
//   A[m=lane&15][k=(lane>>4)*8+j]   B[k=(lane>>4)*8+j][n=lane&15]
//   C: col(n)=lane&15, row(m)=(lane>>4)*4+reg
//   mfma(Xf,Yf) = X·Y^T; X=W2 m-tile, Y=h1 row-tile => C[m=neuron][n=row].
// ---------------------------------------------------------------------------

typedef __attribute__((ext_vector_type(8))) short bf16x8;
typedef __attribute__((ext_vector_type(4))) float f32x4;
typedef __attribute__((ext_vector_type(2))) float f32x2;

#define BLOCK_THREADS 128       // 2 waves
#define ROWS_PER_BLOCK 256      // 2 groups x 128 rows
#define G_ITERS 2

__device__ __forceinline__ float lrelu(float a) {
    return fmaxf(a, 0.01f * a);     // exact leaky_relu(0.01)
}

__device__ __forceinline__ f32x2 lrelu2(f32x2 a) {
    return __builtin_elementwise_max(a, a * 0.01f);   // v_pk_mul + v_pk_max
}

__device__ __forceinline__ float softplus(float v) {
    return fmaxf(v, 0.0f) + log1pf(expf(-fabsf(v)));   // jax.nn.softplus
}

// two fp32 -> packed bf16x2 (hardware RNE), 1 VALU op.
__device__ __forceinline__ unsigned cvt_pk_bf16(float lo, float hi) {
    unsigned r;
    asm("v_cvt_pk_bf16_f32 %0, %1, %2" : "=v"(r) : "v"(lo), "v"(hi));
    return r;
}

__global__ __launch_bounds__(BLOCK_THREADS, 4) void dln_mfma(
    const float* __restrict__ x,
    const float* __restrict__ W1,  const float* __restrict__ b1,
    const float* __restrict__ W2,  const float* __restrict__ b2,
    const float* __restrict__ WLd, const float* __restrict__ bLd,
    const float* __restrict__ WLo, const float* __restrict__ bLo,
    float* __restrict__ out)
{
    __shared__ __align__(16) unsigned short h1s[2][8][64][8];   // 16 KiB

    const int tid  = threadIdx.x;
    const int lane = tid & 63;
    const int wv   = tid >> 6;          // wave id 0..1
    const int quad = lane >> 4;         // 0..3
    const int c    = lane & 15;         // 0..15

    // ---- x loads first: both groups' float4 in flight ---------------------
    const int row0 = blockIdx.x * ROWS_PER_BLOCK + tid;     // group stride 128
    float4 qv[G_ITERS];
    qv[0] = ((const float4*)x)[row0];
    qv[1] = ((const float4*)x)[row0 + 128];

    // ---- preload (once per block, register-resident under the 128 budget):
    //      A-frags = W2 tiles (bf16), head weights + b2 (fp32, lane-indexed)
    bf16x8 afrag[4][2];
    f32x4 wld0[4], wld1[4], wlo[4], b2v[4];
#pragma unroll
    for (int mt = 0; mt < 4; ++mt) {
        const float* wr = W2 + (16 * mt + c) * 64 + 8 * quad;
#pragma unroll
        for (int s = 0; s < 2; ++s) {
            const float4 f0 = *(const float4*)(wr + 32 * s);
            const float4 f1 = *(const float4*)(wr + 32 * s + 4);
            uint4 u;
            u.x = cvt_pk_bf16(f0.x, f0.y);
            u.y = cvt_pk_bf16(f0.z, f0.w);
            u.z = cvt_pk_bf16(f1.x, f1.y);
            u.w = cvt_pk_bf16(f1.z, f1.w);
            afrag[mt][s] = __builtin_bit_cast(bf16x8, u);
        }
        const int nb = 16 * mt + 4 * quad;   // this lane's 16 neurons
        wld0[mt] = *(const f32x4*)(WLd + nb);
        wld1[mt] = *(const f32x4*)(WLd + 64 + nb);
        wlo[mt]  = *(const f32x4*)(WLo + nb);
        b2v[mt]  = *(const f32x4*)(b2 + nb);
    }
    const float bld0 = bLd[0];
    const float bld1 = bLd[1];
    const float blo0 = bLo[0];

#pragma unroll
    for (int g = 0; g < G_ITERS; ++g) {
        const int row_g = row0 + g * 128;

        // ---- phase 1: h1 = lrelu(q@W1^T + b1), bf16 -> LDS (own slot) ----
#pragma unroll
        for (int ch = 0; ch < 8; ++ch) {        // chunk ch holds k=8ch..8ch+7
            unsigned up[4];
#pragma unroll
            for (int p = 0; p < 4; ++p) {
                float h[2];
#pragma unroll
                for (int e = 0; e < 2; ++e) {
                    const int j = ch * 8 + p * 2 + e;
                    float a = b1[j];
                    a = fmaf(qv[g].x, W1[4 * j + 0], a);
                    a = fmaf(qv[g].y, W1[4 * j + 1], a);
                    a = fmaf(qv[g].z, W1[4 * j + 2], a);
                    a = fmaf(qv[g].w, W1[4 * j + 3], a);
                    h[e] = lrelu(a);
                }
                up[p] = cvt_pk_bf16(h[0], h[1]);
            }
            *(uint4*)&h1s[wv][ch][lane][0] = make_uint4(up[0], up[1], up[2], up[3]);
        }
        // No barrier: this wave reads only rows it wrote; per-wave DS ops
        // execute in order (also makes buffer reuse across g safe).

        // ---- phase 2: h2^T tiles via MFMA; heads in-register (pk math) ---
        float sld0 = 0.0f, sld1 = 0.0f, slo = 0.0f;
#pragma unroll
        for (int it = 0; it < 4; ++it) {            // 16 batch rows / iter
            const bf16x8 bf0 = *(const bf16x8*)&h1s[wv][quad][it * 16 + c][0];
            const bf16x8 bf1 = *(const bf16x8*)&h1s[wv][4 + quad][it * 16 + c][0];

            f32x2 pld0 = {0.0f, 0.0f}, pld1 = {0.0f, 0.0f}, plo = {0.0f, 0.0f};
#pragma unroll
            for (int mt = 0; mt < 4; ++mt) {
                f32x4 acc = b2v[mt];                // bias pre-load
                acc = __builtin_amdgcn_mfma_f32_16x16x32_bf16(afrag[mt][0], bf0, acc, 0, 0, 0);
                acc = __builtin_amdgcn_mfma_f32_16x16x32_bf16(afrag[mt][1], bf1, acc, 0, 0, 0);
                // acc[r] = pre-act h2[row it*16+c][neuron 16mt+4quad+r]
                const f32x2 hlo = lrelu2((f32x2){acc[0], acc[1]});
                const f32x2 hhi = lrelu2((f32x2){acc[2], acc[3]});
                pld0 = __builtin_elementwise_fma(hlo, (f32x2){wld0[mt][0], wld0[mt][1]}, pld0);
                pld0 = __builtin_elementwise_fma(hhi, (f32x2){wld0[mt][2], wld0[mt][3]}, pld0);
                pld1 = __builtin_elementwise_fma(hlo, (f32x2){wld1[mt][0], wld1[mt][1]}, pld1);
                pld1 = __builtin_elementwise_fma(hhi, (f32x2){wld1[mt][2], wld1[mt][3]}, pld1);
                plo  = __builtin_elementwise_fma(hlo, (f32x2){wlo[mt][0],  wlo[mt][1]},  plo);
                plo  = __builtin_elementwise_fma(hhi, (f32x2){wlo[mt][2],  wlo[mt][3]},  plo);
            }
            // horizontal add of the pk pairs, then reduce over the 4 quads
            float r0 = pld0[0] + pld0[1];
            float r1 = pld1[0] + pld1[1];
            float r2 = plo[0]  + plo[1];
            r0 += __shfl_xor(r0, 16); r0 += __shfl_xor(r0, 32);
            r1 += __shfl_xor(r1, 16); r1 += __shfl_xor(r1, 32);
            r2 += __shfl_xor(r2, 16); r2 += __shfl_xor(r2, 32);
            // lane(q,c) keeps iteration it==q -> its own row (= lane)
            if (it == quad) { sld0 = r0; sld1 = r1; slo = r2; }
        }

        // ---- epilogue: one row per lane, fully coalesced store -----------
        {
            const float ld0 = softplus(sld0 + bld0);
            const float ld1 = softplus(sld1 + bld1);
            const float lo  = slo + blo0;
            float4 o;
            o.x = fmaf(ld0, ld0, 1e-9f);                  // H00
            o.y = ld0 * lo;                               // H01
            o.z = o.y;                                    // H10
            o.w = fmaf(lo, lo, fmaf(ld1, ld1, 1e-9f));    // H11
            reinterpret_cast<float4*>(out)[row_g] = o;
        }
    }
}

// ---- scalar fallback for tail rows (nrows % 256) --------------------------
__global__ __launch_bounds__(256) void dln_tail(
    const float* __restrict__ x,
    const float* __restrict__ W1,  const float* __restrict__ b1,
    const float* __restrict__ W2,  const float* __restrict__ b2,
    const float* __restrict__ WLd, const float* __restrict__ bLd,
    const float* __restrict__ WLo, const float* __restrict__ bLo,
    float* __restrict__ out, int row0, int nrows)
{
    const int row = row0 + blockIdx.x * 256 + threadIdx.x;
    if (row >= nrows) return;
    const float4 qv = reinterpret_cast<const float4*>(x)[row];
    float h1[64];
#pragma unroll
    for (int j = 0; j < 64; ++j) {
        float a = b1[j];
        a = fmaf(qv.x, W1[4 * j + 0], a);
        a = fmaf(qv.y, W1[4 * j + 1], a);
        a = fmaf(qv.z, W1[4 * j + 2], a);
        a = fmaf(qv.w, W1[4 * j + 3], a);
        h1[j] = lrelu(a);
    }
    float ld0 = bLd[0], ld1 = bLd[1], lo = bLo[0];
#pragma unroll 4
    for (int j = 0; j < 64; ++j) {
        float a0 = b2[j], a1 = 0.0f;
        const float* w = W2 + 64 * j;
#pragma unroll
        for (int k = 0; k < 64; k += 2) {
            a0 = fmaf(h1[k],     w[k],     a0);
            a1 = fmaf(h1[k + 1], w[k + 1], a1);
        }
        const float a = lrelu(a0 + a1);
        ld0 = fmaf(a, WLd[j],      ld0);
        ld1 = fmaf(a, WLd[64 + j], ld1);
        lo  = fmaf(a, WLo[j],      lo);
    }
    ld0 = softplus(ld0);
    ld1 = softplus(ld1);
    float4 o;
    o.x = fmaf(ld0, ld0, 1e-9f);
    o.y = ld0 * lo;
    o.z = o.y;
    o.w = fmaf(lo, lo, fmaf(ld1, ld1, 1e-9f));
    reinterpret_cast<float4*>(out)[row] = o;
}

extern "C" void kernel_launch(void* const* d_in, const int* in_sizes, int n_in,
                              void* d_out, int out_size, void* d_ws, size_t ws_size,
                              hipStream_t stream)
{
    const float* x   = (const float*)d_in[0];
    const float* W1  = (const float*)d_in[1];
    const float* b1  = (const float*)d_in[2];
    const float* W2  = (const float*)d_in[3];
    const float* b2  = (const float*)d_in[4];
    const float* WLd = (const float*)d_in[5];
    const float* bLd = (const float*)d_in[6];
    const float* WLo = (const float*)d_in[7];
    const float* bLo = (const float*)d_in[8];
    float* out = (float*)d_out;

    const int nrows = in_sizes[0] / 4;             // x is (nrows, 4) fp32
    const int nfull = nrows / ROWS_PER_BLOCK;
    const int rem   = nrows - nfull * ROWS_PER_BLOCK;

    if (nfull > 0)
        dln_mfma<<<nfull, BLOCK_THREADS, 0, stream>>>(
            x, W1, b1, W2, b2, WLd, bLd, WLo, bLo, out);
    if (rem > 0)
        dln_tail<<<(rem + 255) / 256, 256, 0, stream>>>(
            x, W1, b1, W2, b2, WLd, bLd, WLo, bLo, out,
            nfull * ROWS_PER_BLOCK, nrows);
}

// Round 5
// 119.838 us; speedup vs baseline: 1.5851x; 1.5851x over previous
//
#include <hip/hip_runtime.h>

// ---------------------------------------------------------------------------
// DeepLagrangianNetwork head, MFMA version — round 9 (persistent blocks).
// Round-8 post-mortem: __launch_bounds__ second arg (min waves/EU) clamps the
// allocator to 64 VGPRs and forces ~370 MB of scratch spill (twice confirmed:
// rounds 6 & 8). NEVER pass it on this kernel.
// Cross-round invariant: rounds 0/5/7 (very different kernels, same 4096-wg
// grid) all land 55-63 us with only ~3-4 blocks/CU resident. Theory: wall
// time is dominated by workgroup turnover (~4-5 dispatch generations),
// not per-wave issue (~2.5K cy/wave vs 132K cy kernel).
// This round: ONE generation. grid = 1024 blocks (4/CU, all resident:
// 32 KiB LDS x 4 = 128 <= 160 KiB), each block loops 4 iterations x 256 rows
// (grid-stride, stripe = 262144 rows) with software-pipelined x prefetch.
// Weight preload amortized 4x further. Zero __syncthreads throughout
// (wave-self-contained; LDS reuse across iterations is safe because per-wave
// DS ops execute in program order).
// Per row: h1 = lrelu(q@W1^T+b1)  (4->64, VALU, v_cvt_pk_bf16 packing)
//          h2^T = W2 @ h1^T       (bf16 MFMA 16x16x32, A = W2 tiles)
//          heads (Ld, Lo) on fp32 h2 in-register (packed v_pk_fma_f32),
//          quad-reduced via shfl_xor; H = L L^T + 1e-9 I, float4/row store.
// Fragment layouts (m89/m120-verified):
//   A[m=lane&15][k=(lane>>4)*8+j]   B[k=(lane>>4)*8+j][n=lane&15]
//   C: col(n)=lane&15, row(m)=(lane>>4)*4+reg
//   mfma(Xf,Yf) = X.Y^T; X=W2 m-tile, Y=h1 row-tile => C[m=neuron][n=row].
// ---------------------------------------------------------------------------

typedef __attribute__((ext_vector_type(8))) short bf16x8;
typedef __attribute__((ext_vector_type(4))) float f32x4;
typedef __attribute__((ext_vector_type(2))) float f32x2;

#define BLOCK_THREADS 256       // 4 waves
#define GRID_BLOCKS   1024      // 4 blocks/CU on 256 CUs — single generation

__device__ __forceinline__ float lrelu(float a) {
    return fmaxf(a, 0.01f * a);     // exact leaky_relu(0.01)
}

__device__ __forceinline__ f32x2 lrelu2(f32x2 a) {
    return __builtin_elementwise_max(a, a * 0.01f);   // v_pk_mul + v_pk_max
}

__device__ __forceinline__ float softplus(float v) {
    return fmaxf(v, 0.0f) + log1pf(expf(-fabsf(v)));   // jax.nn.softplus
}

// two fp32 -> packed bf16x2 (hardware RNE), 1 VALU op.
__device__ __forceinline__ unsigned cvt_pk_bf16(float lo, float hi) {
    unsigned r;
    asm("v_cvt_pk_bf16_f32 %0, %1, %2" : "=v"(r) : "v"(lo), "v"(hi));
    return r;
}

__global__ __launch_bounds__(BLOCK_THREADS) void dln_mfma(
    const float* __restrict__ x,
    const float* __restrict__ W1,  const float* __restrict__ b1,
    const float* __restrict__ W2,  const float* __restrict__ b2,
    const float* __restrict__ WLd, const float* __restrict__ bLd,
    const float* __restrict__ WLo, const float* __restrict__ bLo,
    float* __restrict__ out,
    int iters, int iter_stride)
{
    __shared__ __align__(16) unsigned short h1s[4][8][64][8];   // 32 KiB

    const int tid  = threadIdx.x;
    const int lane = tid & 63;
    const int wv   = tid >> 6;          // wave id 0..3
    const int quad = lane >> 4;         // 0..3
    const int c    = lane & 15;         // 0..15

    // ---- first x load in flight before anything else ----------------------
    int row = blockIdx.x * BLOCK_THREADS + tid;
    float4 qnext = ((const float4*)x)[row];

    // ---- preload (once per block, amortized over `iters` stripes):
    //      A-frags = W2 tiles (bf16), head weights + b2 (fp32, lane-indexed)
    bf16x8 afrag[4][2];
    f32x4 wld0[4], wld1[4], wlo[4], b2v[4];
#pragma unroll
    for (int mt = 0; mt < 4; ++mt) {
        const float* wr = W2 + (16 * mt + c) * 64 + 8 * quad;
#pragma unroll
        for (int s = 0; s < 2; ++s) {
            const float4 f0 = *(const float4*)(wr + 32 * s);
            const float4 f1 = *(const float4*)(wr + 32 * s + 4);
            uint4 u;
            u.x = cvt_pk_bf16(f0.x, f0.y);
            u.y = cvt_pk_bf16(f0.z, f0.w);
            u.z = cvt_pk_bf16(f1.x, f1.y);
            u.w = cvt_pk_bf16(f1.z, f1.w);
            afrag[mt][s] = __builtin_bit_cast(bf16x8, u);
        }
        const int nb = 16 * mt + 4 * quad;   // this lane's 16 neurons
        wld0[mt] = *(const f32x4*)(WLd + nb);
        wld1[mt] = *(const f32x4*)(WLd + 64 + nb);
        wlo[mt]  = *(const f32x4*)(WLo + nb);
        b2v[mt]  = *(const f32x4*)(b2 + nb);
    }
    const float bld0 = bLd[0];
    const float bld1 = bLd[1];
    const float blo0 = bLo[0];

    for (int itr = 0; itr < iters; ++itr) {
        const float4 qv = qnext;
        const int row_cur = row;
        row += iter_stride;
        if (itr + 1 < iters)                 // uniform branch
            qnext = ((const float4*)x)[row]; // prefetch next stripe

        // ---- phase 1: h1 = lrelu(q@W1^T + b1), bf16 -> LDS (own slot) ----
#pragma unroll
        for (int ch = 0; ch < 8; ++ch) {        // chunk ch holds k=8ch..8ch+7
            unsigned up[4];
#pragma unroll
            for (int p = 0; p < 4; ++p) {
                float h[2];
#pragma unroll
                for (int e = 0; e < 2; ++e) {
                    const int j = ch * 8 + p * 2 + e;
                    float a = b1[j];
                    a = fmaf(qv.x, W1[4 * j + 0], a);
                    a = fmaf(qv.y, W1[4 * j + 1], a);
                    a = fmaf(qv.z, W1[4 * j + 2], a);
                    a = fmaf(qv.w, W1[4 * j + 3], a);
                    h[e] = lrelu(a);
                }
                up[p] = cvt_pk_bf16(h[0], h[1]);
            }
            *(uint4*)&h1s[wv][ch][lane][0] = make_uint4(up[0], up[1], up[2], up[3]);
        }
        // No barrier: this wave reads only rows it wrote; per-wave DS ops
        // execute in order (also makes buffer reuse across iterations safe).

        // ---- phase 2: h2^T tiles via MFMA; heads in-register (pk math) ---
        float sld0 = 0.0f, sld1 = 0.0f, slo = 0.0f;
#pragma unroll
        for (int it = 0; it < 4; ++it) {            // 16 batch rows / iter
            const bf16x8 bf0 = *(const bf16x8*)&h1s[wv][quad][it * 16 + c][0];
            const bf16x8 bf1 = *(const bf16x8*)&h1s[wv][4 + quad][it * 16 + c][0];

            f32x2 pld0 = {0.0f, 0.0f}, pld1 = {0.0f, 0.0f}, plo = {0.0f, 0.0f};
#pragma unroll
            for (int mt = 0; mt < 4; ++mt) {
                f32x4 acc = b2v[mt];                // bias pre-load
                acc = __builtin_amdgcn_mfma_f32_16x16x32_bf16(afrag[mt][0], bf0, acc, 0, 0, 0);
                acc = __builtin_amdgcn_mfma_f32_16x16x32_bf16(afrag[mt][1], bf1, acc, 0, 0, 0);
                // acc[r] = pre-act h2[row it*16+c][neuron 16mt+4quad+r]
                const f32x2 hlo = lrelu2((f32x2){acc[0], acc[1]});
                const f32x2 hhi = lrelu2((f32x2){acc[2], acc[3]});
                pld0 = __builtin_elementwise_fma(hlo, (f32x2){wld0[mt][0], wld0[mt][1]}, pld0);
                pld0 = __builtin_elementwise_fma(hhi, (f32x2){wld0[mt][2], wld0[mt][3]}, pld0);
                pld1 = __builtin_elementwise_fma(hlo, (f32x2){wld1[mt][0], wld1[mt][1]}, pld1);
                pld1 = __builtin_elementwise_fma(hhi, (f32x2){wld1[mt][2], wld1[mt][3]}, pld1);
                plo  = __builtin_elementwise_fma(hlo, (f32x2){wlo[mt][0],  wlo[mt][1]},  plo);
                plo  = __builtin_elementwise_fma(hhi, (f32x2){wlo[mt][2],  wlo[mt][3]},  plo);
            }
            // horizontal add of the pk pairs, then reduce over the 4 quads
            float r0 = pld0[0] + pld0[1];
            float r1 = pld1[0] + pld1[1];
            float r2 = plo[0]  + plo[1];
            r0 += __shfl_xor(r0, 16); r0 += __shfl_xor(r0, 32);
            r1 += __shfl_xor(r1, 16); r1 += __shfl_xor(r1, 32);
            r2 += __shfl_xor(r2, 16); r2 += __shfl_xor(r2, 32);
            // lane(q,c) keeps iteration it==q -> its own row (= lane)
            if (it == quad) { sld0 = r0; sld1 = r1; slo = r2; }
        }

        // ---- epilogue: one row per lane, fully coalesced store -----------
        {
            const float ld0 = softplus(sld0 + bld0);
            const float ld1 = softplus(sld1 + bld1);
            const float lo  = slo + blo0;
            float4 o;
            o.x = fmaf(ld0, ld0, 1e-9f);                  // H00
            o.y = ld0 * lo;                               // H01
            o.z = o.y;                                    // H10
            o.w = fmaf(lo, lo, fmaf(ld1, ld1, 1e-9f));    // H11
            reinterpret_cast<float4*>(out)[row_cur] = o;
        }
    }
}

// ---- scalar fallback for tail rows ----------------------------------------
__global__ __launch_bounds__(256) void dln_tail(
    const float* __restrict__ x,
    const float* __restrict__ W1,  const float* __restrict__ b1,
    const float* __restrict__ W2,  const float* __restrict__ b2,
    const float* __restrict__ WLd, const float* __restrict__ bLd,
    const float* __restrict__ WLo, const float* __restrict__ bLo,
    float* __restrict__ out, int row0, int nrows)
{
    const int row = row0 + blockIdx.x * 256 + threadIdx.x;
    if (row >= nrows) return;
    const float4 qv = reinterpret_cast<const float4*>(x)[row];
    float h1[64];
#pragma unroll
    for (int j = 0; j < 64; ++j) {
        float a = b1[j];
        a = fmaf(qv.x, W1[4 * j + 0], a);
        a = fmaf(qv.y, W1[4 * j + 1], a);
        a = fmaf(qv.z, W1[4 * j + 2], a);
        a = fmaf(qv.w, W1[4 * j + 3], a);
        h1[j] = lrelu(a);
    }
    float ld0 = bLd[0], ld1 = bLd[1], lo = bLo[0];
#pragma unroll 4
    for (int j = 0; j < 64; ++j) {
        float a0 = b2[j], a1 = 0.0f;
        const float* w = W2 + 64 * j;
#pragma unroll
        for (int k = 0; k < 64; k += 2) {
            a0 = fmaf(h1[k],     w[k],     a0);
            a1 = fmaf(h1[k + 1], w[k + 1], a1);
        }
        const float a = lrelu(a0 + a1);
        ld0 = fmaf(a, WLd[j],      ld0);
        ld1 = fmaf(a, WLd[64 + j], ld1);
        lo  = fmaf(a, WLo[j],      lo);
    }
    ld0 = softplus(ld0);
    ld1 = softplus(ld1);
    float4 o;
    o.x = fmaf(ld0, ld0, 1e-9f);
    o.y = ld0 * lo;
    o.z = o.y;
    o.w = fmaf(lo, lo, fmaf(ld1, ld1, 1e-9f));
    reinterpret_cast<float4*>(out)[row] = o;
}

extern "C" void kernel_launch(void* const* d_in, const int* in_sizes, int n_in,
                              void* d_out, int out_size, void* d_ws, size_t ws_size,
                              hipStream_t stream)
{
    const float* x   = (const float*)d_in[0];
    const float* W1  = (const float*)d_in[1];
    const float* b1  = (const float*)d_in[2];
    const float* W2  = (const float*)d_in[3];
    const float* b2  = (const float*)d_in[4];
    const float* WLd = (const float*)d_in[5];
    const float* bLd = (const float*)d_in[6];
    const float* WLo = (const float*)d_in[7];
    const float* bLo = (const float*)d_in[8];
    float* out = (float*)d_out;

    const int nrows  = in_sizes[0] / 4;             // x is (nrows, 4) fp32
    const int stripe = GRID_BLOCKS * BLOCK_THREADS; // 262144 rows / stripe
    const int iters  = nrows / stripe;
    const int nfull  = iters * stripe;
    const int rem    = nrows - nfull;

    if (iters > 0)
        dln_mfma<<<GRID_BLOCKS, BLOCK_THREADS, 0, stream>>>(
            x, W1, b1, W2, b2, WLd, bLd, WLo, bLo, out, iters, stripe);
    if (rem > 0)
        dln_tail<<<(rem + 255) / 256, 256, 0, stream>>>(
            x, W1, b1, W2, b2, WLd, bLd, WLo, bLo, out, nfull, nrows);
}